// Round 10
// baseline (205.243 us; speedup 1.0000x reference)
//
#include <hip/hip_runtime.h>
#include <hip/hip_bf16.h>

typedef __attribute__((ext_vector_type(8))) __bf16 bf16x8;
typedef __attribute__((ext_vector_type(4))) float floatx4;
typedef __attribute__((ext_vector_type(2))) unsigned short us2;
typedef __attribute__((ext_vector_type(4))) unsigned short us4;
typedef __attribute__((ext_vector_type(8))) unsigned short us8;
typedef __attribute__((ext_vector_type(4))) short s16x4;
typedef __attribute__((ext_vector_type(2))) unsigned int uint2v;

#define MFMA16(A, B, C) __builtin_amdgcn_mfma_f32_16x16x32_bf16((A), (B), (C), 0, 0, 0)
#define MFMA1K(A, B, C) __builtin_amdgcn_mfma_f32_16x16x16bf16_1k((A), (B), (C), 0, 0, 0)

#define LOG2E 1.44269504088896340736f

static __device__ __forceinline__ unsigned short f2bfbits(float f) {
    __hip_bfloat16 h = __float2bfloat16(f);
    union { __hip_bfloat16 h; unsigned short u; } cv;
    cv.h = h;
    return cv.u;
}
// fast bf16 RNE (finite moderate values only)
static __device__ __forceinline__ unsigned int rne32(float f) {
    unsigned int u = __builtin_bit_cast(unsigned int, f);
    return u + 0x7fffu + ((u >> 16) & 1u);
}
static __device__ __forceinline__ unsigned short rne16(float f) {
    return (unsigned short)(rne32(f) >> 16);
}
static __device__ __forceinline__ bf16x8 cvt8(floatx4 a, floatx4 b) {
    us8 u;
#pragma unroll
    for (int i = 0; i < 4; i++) { u[i] = rne16(a[i]); u[4 + i] = rne16(b[i]); }
    return __builtin_bit_cast(bf16x8, u);
}
static __device__ __forceinline__ bf16x8 load_bf8(const __hip_bfloat16* p) {
    return *reinterpret_cast<const bf16x8*>(p);
}
static __device__ __forceinline__ float bf2f(unsigned short u) {
    unsigned int w = ((unsigned int)u) << 16;
    return __builtin_bit_cast(float, w);
}

// exp2 of 4 values + truncation-pack to 4 bf16, in ONE asm block:
// 4x v_exp_f32 + 2x v_perm_b32 (6 VALU inst). Trans-use hazard satisfied by
// instruction spacing (>=1 intervening inst before each consumer).
static __device__ __forceinline__ s16x4 exp4_pack(float a0, float a1, float a2, float a3) {
    float r0, r1, r2, r3;
    unsigned int lo, hi;
    asm("v_exp_f32 %0, %6\n\t"
        "v_exp_f32 %1, %7\n\t"
        "v_exp_f32 %2, %8\n\t"
        "v_exp_f32 %3, %9\n\t"
        "v_perm_b32 %4, %1, %0, %10\n\t"
        "v_perm_b32 %5, %3, %2, %10"
        : "=&v"(r0), "=&v"(r1), "=&v"(r2), "=&v"(r3), "=&v"(lo), "=v"(hi)
        : "v"(a0), "v"(a1), "v"(a2), "v"(a3), "s"(0x07060302u));
    uint2v u = {lo, hi};
    return __builtin_bit_cast(s16x4, u);
}
// exp2(a) + exp2(b) in one asm block (s_nop covers the 1 trans-use wait state).
static __device__ __forceinline__ float exp2_add(float a, float b) {
    float r0, r1, s;
    asm("v_exp_f32 %0, %3\n\t"
        "v_exp_f32 %1, %4\n\t"
        "s_nop 0\n\t"
        "v_add_f32 %2, %0, %1"
        : "=&v"(r0), "=&v"(r1), "=v"(s)
        : "v"(a), "v"(b));
    return s;
}
// truncation pack (epilogue): 2x v_perm
static __device__ __forceinline__ s16x4 pack4t(float e0, float e1, float e2, float e3) {
    unsigned int b0 = __builtin_bit_cast(unsigned int, e0);
    unsigned int b1 = __builtin_bit_cast(unsigned int, e1);
    unsigned int b2 = __builtin_bit_cast(unsigned int, e2);
    unsigned int b3 = __builtin_bit_cast(unsigned int, e3);
    uint2v u = {__builtin_amdgcn_perm(b1, b0, 0x07060302u),
                __builtin_amdgcn_perm(b3, b2, 0x07060302u)};
    return __builtin_bit_cast(s16x4, u);
}

// Fragment layouts (16-row tile = 1024 bf16):
//   qf/kf[tile][h(2)][lane(64)][e(8)]: M[tile*16 + (lane&15)][h*32 + (lane>>4)*8 + e]
//   vf/vfs[tile][t(4)][lane(64)][e(4)]: V[tile*16 + (lane>>4)*4 + e][t*16 + (lane&15)]
// K is pre-scaled by log2(e) (weights+bias) so exp(s) == exp2(s').

// ---------------------------------------------------------------------------
// K0: wT[p][d][c] = dw_p[c] * pw_p[c][d]  (K scaled by log2e)
// ---------------------------------------------------------------------------
__global__ __launch_bounds__(256) void prep_w(
    const float* __restrict__ dwq, const float* __restrict__ pwq,
    const float* __restrict__ dwk, const float* __restrict__ pwk,
    const float* __restrict__ dwv, const float* __restrict__ pwv,
    __hip_bfloat16* __restrict__ wT)
{
    int idx = blockIdx.x * 256 + threadIdx.x;   // < 49152
    int p = idx >> 14;
    int r = idx & 16383;
    int d = r >> 8, c = r & 255;
    const float* dw = (p == 0) ? dwq : ((p == 1) ? dwk : dwv);
    const float* pw = (p == 0) ? pwq : ((p == 1) ? pwk : pwv);
    float scale = (p == 1) ? LOG2E : 1.0f;
    wT[idx] = __float2bfloat16(dw[c] * pw[c * 64 + d] * scale);
}

// ---------------------------------------------------------------------------
// K1: QKV projection, one wave per (tile, proj): 768 blocks.
// ---------------------------------------------------------------------------
__global__ __launch_bounds__(256) void proj_qkv(
    const float* __restrict__ x,
    const __hip_bfloat16* __restrict__ wT,
    const float* __restrict__ bqp, const float* __restrict__ bkp,
    const float* __restrict__ bvp,
    __hip_bfloat16* __restrict__ qf, __hip_bfloat16* __restrict__ kf,
    __hip_bfloat16* __restrict__ vf)
{
    int wg = blockIdx.x * 4 + (threadIdx.x >> 6);   // 0..3071
    int p = wg >> 10;                                // 0=q 1=k 2=v
    int wid = wg & 1023;                             // tile
    int lane = threadIdx.x & 63;
    int l15 = lane & 15, quad = lane >> 4;
    int strip = wid << 4;

    floatx4 acc[4];
#pragma unroll
    for (int t = 0; t < 4; t++) acc[t] = (floatx4){0.f, 0.f, 0.f, 0.f};

    const float* xrow = x + (strip + l15) * 256 + quad * 8;
    const __hip_bfloat16* wp = wT + p * 16384;
#pragma unroll
    for (int ks = 0; ks < 8; ks++) {
        floatx4 xa = *reinterpret_cast<const floatx4*>(xrow + ks * 32);
        floatx4 xb = *reinterpret_cast<const floatx4*>(xrow + ks * 32 + 4);
        bf16x8 a = cvt8(xa, xb);
#pragma unroll
        for (int t = 0; t < 4; t++) {
            bf16x8 b = load_bf8(wp + (t * 16 + l15) * 256 + ks * 32 + quad * 8);
            acc[t] = MFMA16(a, b, acc[t]);
        }
    }
    if (p < 2) {
        __hip_bfloat16* dst = (p == 0) ? qf : kf;
        const float* bias = (p == 0) ? bqp : bkp;
        float bscale = (p == 1) ? LOG2E : 1.0f;
#pragma unroll
        for (int t = 0; t < 4; t++) {
            float bsv = bias[t * 16 + l15] * bscale;
            int off0 = wid * 1024 + (t >> 1) * 512 +
                       (((((t & 1) << 1) | (l15 >> 3)) * 16 + quad * 4) * 8) + (l15 & 7);
#pragma unroll
            for (int r = 0; r < 4; r++)
                dst[off0 + r * 8] = __float2bfloat16(acc[t][r] + bsv);
        }
    } else {
#pragma unroll
        for (int t = 0; t < 4; t++) {
            float bsv = bvp[t * 16 + l15];
            us4 pk;
#pragma unroll
            for (int r = 0; r < 4; r++) pk[r] = f2bfbits(acc[t][r] + bsv);
            *reinterpret_cast<us4*>(vf + (wid * 4 + t) * 256 + lane * 4) = pk;
        }
    }
}

// ---------------------------------------------------------------------------
// K2: 512 blocks x 512 thr; block = 2 i-tiles, 8 waves split j.
// rl_i = 1/sum_j exp2(s'_ij); tail writes vfs = vf * rl.
// ---------------------------------------------------------------------------
__global__ __launch_bounds__(512) void pass1_rl(
    const __hip_bfloat16* __restrict__ qf, const __hip_bfloat16* __restrict__ kf,
    const __hip_bfloat16* __restrict__ vf, __hip_bfloat16* __restrict__ vfs)
{
    int itg0 = blockIdx.x * 2;            // i-tiles itg0, itg0+1 (same n)
    int n = itg0 >> 8;
    int jw = threadIdx.x >> 6;            // 0..7
    int lane = threadIdx.x & 63;
    int l15 = lane & 15, quad = lane >> 4;

    const __hip_bfloat16* kp = kf + itg0 * 1024 + lane * 8;
    bf16x8 a0 = load_bf8(kp);
    bf16x8 a1 = load_bf8(kp + 512);
    bf16x8 a2 = load_bf8(kp + 1024);
    bf16x8 a3 = load_bf8(kp + 1536);

    floatx4 lsA = (floatx4){0.f, 0.f, 0.f, 0.f};
    floatx4 lsB = (floatx4){0.f, 0.f, 0.f, 0.f};
    const __hip_bfloat16* qp0 = qf + (n * 256 + jw * 32) * 1024 + lane * 8;
    for (int it = 0; it < 16; it++, qp0 += 2048) {
        bf16x8 b0 = load_bf8(qp0);
        bf16x8 b1 = load_bf8(qp0 + 512);
        bf16x8 b2 = load_bf8(qp0 + 1024);
        bf16x8 b3 = load_bf8(qp0 + 1536);
        floatx4 z = (floatx4){0.f, 0.f, 0.f, 0.f};
        floatx4 sA0 = MFMA16(a1, b1, MFMA16(a0, b0, z));
        floatx4 sA1 = MFMA16(a1, b3, MFMA16(a0, b2, z));
        floatx4 sB0 = MFMA16(a3, b1, MFMA16(a2, b0, z));
        floatx4 sB1 = MFMA16(a3, b3, MFMA16(a2, b2, z));
#pragma unroll
        for (int r = 0; r < 4; r++) {
            lsA[r] += exp2_add(sA0[r], sA1[r]);
            lsB[r] += exp2_add(sB0[r], sB1[r]);
        }
    }
#pragma unroll
    for (int m = 1; m < 16; m <<= 1) {
#pragma unroll
        for (int r = 0; r < 4; r++) {
            lsA[r] += __shfl_xor(lsA[r], m, 64);
            lsB[r] += __shfl_xor(lsB[r], m, 64);
        }
    }
    __shared__ float red[8][32];
    __shared__ float rls[32];
    if (l15 == 0) {
#pragma unroll
        for (int r = 0; r < 4; r++) {
            red[jw][quad * 4 + r] = lsA[r];
            red[jw][16 + quad * 4 + r] = lsB[r];
        }
    }
    __syncthreads();
    if (threadIdx.x < 32) {
        float tot = 0.f;
#pragma unroll
        for (int w = 0; w < 8; w++) tot += red[w][threadIdx.x];
        rls[threadIdx.x] = 1.0f / tot;
    }
    __syncthreads();
    // vfs = vf * rl(row); elem m in tile: row = ((m>>6)&3)*4 + (m&3)
    int m0 = threadIdx.x * 4;             // 0..2044, covers 2 tiles
    int toff = m0 >> 10;                  // 0/1
    int mm = m0 & 1023;                   // aligned to 4 -> rows consecutive
    int rb = toff * 16 + ((mm >> 6) & 3) * 4;
    const unsigned short* vin = reinterpret_cast<const unsigned short*>(vf) + itg0 * 1024 + m0;
    us4 vv = *reinterpret_cast<const us4*>(vin);
    us4 ov;
#pragma unroll
    for (int r = 0; r < 4; r++) ov[r] = rne16(bf2f(vv[r]) * rls[rb + r]);
    *reinterpret_cast<us4*>(reinterpret_cast<unsigned short*>(vfs) + itg0 * 1024 + m0) = ov;
}

// ---------------------------------------------------------------------------
// K3: attT partials. 2048 blocks x 256 (8192 waves = 100% grid occupancy);
// block = (n, jg of 8 j-tiles, ih of 16); wave = 2 j-tiles, 16 i-iters.
// S chained-MFMA; exp+pack fused into one 6-inst asm block (truncation).
// ---------------------------------------------------------------------------
__global__ __launch_bounds__(256) void pass2_att(
    const __hip_bfloat16* __restrict__ qf, const __hip_bfloat16* __restrict__ kf,
    const __hip_bfloat16* __restrict__ vfs,
    unsigned short* __restrict__ attp)
{
    int b = blockIdx.x;          // 0..2047
    int ih = b & 15;
    int g = b >> 4;              // 0..127
    int n = g >> 5;
    int jg = g & 31;
    int w = threadIdx.x >> 6;
    int jt0 = jg * 8 + w * 2;    // local j-tiles jt0, jt0+1
    int lane = threadIdx.x & 63;
    int l15 = lane & 15, quad = lane >> 4;

    const __hip_bfloat16* qp = qf + (n * 256 + jt0) * 1024 + lane * 8;
    bf16x8 bq00 = load_bf8(qp);
    bf16x8 bq01 = load_bf8(qp + 512);
    bf16x8 bq10 = load_bf8(qp + 1024);
    bf16x8 bq11 = load_bf8(qp + 1536);

    floatx4 acc0[4], acc1[4];
#pragma unroll
    for (int t = 0; t < 4; t++) {
        acc0[t] = (floatx4){0.f, 0.f, 0.f, 0.f};
        acc1[t] = (floatx4){0.f, 0.f, 0.f, 0.f};
    }

    int it0 = n * 256 + ih * 16;
    const __hip_bfloat16* kp = kf + it0 * 1024 + lane * 8;
    const __hip_bfloat16* vp = vfs + it0 * 1024;
    for (int it = 0; it < 16; it++, kp += 1024, vp += 1024) {
        bf16x8 a0 = load_bf8(kp);
        bf16x8 a1 = load_bf8(kp + 512);
        floatx4 z = (floatx4){0.f, 0.f, 0.f, 0.f};
        floatx4 s0 = MFMA16(a1, bq01, MFMA16(a0, bq00, z));
        floatx4 s1 = MFMA16(a1, bq11, MFMA16(a0, bq10, z));
        s16x4 p0 = exp4_pack(s0[0], s0[1], s0[2], s0[3]);
        s16x4 p1 = exp4_pack(s1[0], s1[1], s1[2], s1[3]);
#pragma unroll
        for (int t = 0; t < 4; t++) {
            s16x4 bv = *reinterpret_cast<const s16x4*>(vp + t * 256 + lane * 4);
            acc0[t] = MFMA1K(p0, bv, acc0[t]);
            acc1[t] = MFMA1K(p1, bv, acc1[t]);
        }
    }
    unsigned short* op0 = attp + ih * 1048576;
#pragma unroll
    for (int t = 0; t < 4; t++) {
        s16x4 k0 = pack4t(acc0[t][0], acc0[t][1], acc0[t][2], acc0[t][3]);
        s16x4 k1 = pack4t(acc1[t][0], acc1[t][1], acc1[t][2], acc1[t][3]);
        unsigned short* op = op0 + (n * 64 + t * 16 + l15) * 4096 + jt0 * 16 + quad * 4;
        *reinterpret_cast<s16x4*>(op) = k0;
        *reinterpret_cast<s16x4*>(op + 16) = k1;
    }
}

// ---------------------------------------------------------------------------
// K4: final sepconv + residual, summing 16 bf16 i-partials (us2 reads).
// ---------------------------------------------------------------------------
__global__ __launch_bounds__(256) void final_out(
    const unsigned short* __restrict__ attp, const float* __restrict__ gco,
    const float* __restrict__ dwa, const float* __restrict__ pwa,
    const float* __restrict__ ba, float* __restrict__ out)
{
    int b = blockIdx.x;       // 2048 blocks
    int n = b >> 9;
    int hh = (b >> 3) & 63;
    int w0 = (b & 7) << 3;
    __shared__ float g[512];
    int tid = threadIdx.x;
    const unsigned short* ap = attp + (n * 64 + hh) * 4096 + w0 * 64;
    {
        float v0 = 0.f, v1 = 0.f;
#pragma unroll
        for (int ph = 0; ph < 16; ph++) {
            us2 vv = *reinterpret_cast<const us2*>(ap + ph * 1048576 + tid * 2);
            v0 += bf2f(vv[0]);
            v1 += bf2f(vv[1]);
        }
        g[tid * 2]     = v0 * dwa[(tid * 2) & 63];
        g[tid * 2 + 1] = v1 * dwa[(tid * 2 + 1) & 63];
    }
    __syncthreads();
    float acc[8];
#pragma unroll
    for (int w = 0; w < 8; w++) acc[w] = 0.f;
    for (int cc = 0; cc < 64; cc++) {
        float p = pwa[cc * 256 + tid];
#pragma unroll
        for (int w = 0; w < 8; w++) acc[w] += g[w * 64 + cc] * p;
    }
    float bb = ba[tid];
#pragma unroll
    for (int w = 0; w < 8; w++) {
        int pos = (n * 64 + hh) * 64 + w0 + w;
        float gv = gco[pos * 256 + tid];
        out[pos * 256 + tid] = gv * (acc[w] + bb) + gv;
    }
}

// ---------------------------------------------------------------------------
extern "C" void kernel_launch(void* const* d_in, const int* in_sizes, int n_in,
                              void* d_out, int out_size, void* d_ws, size_t ws_size,
                              hipStream_t stream) {
    const float* x   = (const float*)d_in[0];
    const float* gco = (const float*)d_in[1];
    const float* dwq = (const float*)d_in[2];
    const float* pwq = (const float*)d_in[3];
    const float* bq  = (const float*)d_in[4];
    const float* dwk = (const float*)d_in[5];
    const float* pwk = (const float*)d_in[6];
    const float* bk  = (const float*)d_in[7];
    const float* dwv = (const float*)d_in[8];
    const float* pwv = (const float*)d_in[9];
    const float* bv  = (const float*)d_in[10];
    const float* dwa = (const float*)d_in[11];
    const float* pwa = (const float*)d_in[12];
    const float* ba  = (const float*)d_in[13];
    float* out = (float*)d_out;

    char* ws = (char*)d_ws;
    __hip_bfloat16* wT  = (__hip_bfloat16*)ws;                    // 98304 B
    __hip_bfloat16* qf  = (__hip_bfloat16*)(ws + 98304);          // 2 MB
    __hip_bfloat16* kf  = (__hip_bfloat16*)(ws + 2195456);        // 2 MB
    __hip_bfloat16* vf  = (__hip_bfloat16*)(ws + 4292608);        // 2 MB
    __hip_bfloat16* vfs = (__hip_bfloat16*)(ws + 6389760);        // 2 MB
    unsigned short* attp = (unsigned short*)(ws + 8486912);       // 16 x 2 MB bf16

    prep_w<<<192, 256, 0, stream>>>(dwq, pwq, dwk, pwk, dwv, pwv, wT);
    proj_qkv<<<768, 256, 0, stream>>>(x, wT, bq, bk, bv, qf, kf, vf);
    pass1_rl<<<512, 512, 0, stream>>>(qf, kf, vf, vfs);
    pass2_att<<<2048, 256, 0, stream>>>(qf, kf, vfs, attp);
    final_out<<<2048, 256, 0, stream>>>(attp, gco, dwa, pwa, ba, out);
}